// Round 3
// baseline (1606.434 us; speedup 1.0000x reference)
//
#include <hip/hip_runtime.h>

// Dims fixed by the problem
#define N_HW 65536
#define BATCH 4

// ---------------------------------------------------------------------------
// Fold LN affine params into conv weights:
//  Wf[o][i] = W[o][i]*ln_w[i];  S[o] = sum_i Wf[o][i];  bias[o] = sum_i W[o][i]*ln_b[i]
// ---------------------------------------------------------------------------
__global__ __launch_bounds__(192) void fold_kernel(
    const float* __restrict__ Wq, const float* __restrict__ lnqw, const float* __restrict__ lnqb,
    const float* __restrict__ Wkv, const float* __restrict__ lnkw, const float* __restrict__ lnkb,
    float* __restrict__ Wqf, float* __restrict__ biasq, float* __restrict__ Sq,
    float* __restrict__ Wkvf, float* __restrict__ biaskv, float* __restrict__ Skv)
{
    int o = blockIdx.x * 192 + threadIdx.x;
    if (o < 128) {
        float s = 0.f, bb = 0.f;
        for (int i = 0; i < 128; ++i) {
            float w0 = Wq[o*128+i];
            float wf = w0 * lnqw[i];
            Wqf[o*128+i] = wf;
            s += wf;
            bb += w0 * lnqb[i];
        }
        Sq[o] = s; biasq[o] = bb;
    } else if (o < 384) {
        int o2 = o - 128;
        float s = 0.f, bb = 0.f;
        for (int i = 0; i < 128; ++i) {
            float w0 = Wkv[o2*128+i];
            float wf = w0 * lnkw[i];
            Wkvf[o2*128+i] = wf;
            s += wf;
            bb += w0 * lnkb[i];
        }
        Skv[o2] = s; biaskv[o2] = bb;
    }
}

// ---------------------------------------------------------------------------
// Per-position LayerNorm stats over C=128. Full batch (grid 1024 x 256 thr).
// ---------------------------------------------------------------------------
__global__ __launch_bounds__(256) void lnstats_kernel(
    const float* __restrict__ X, float* __restrict__ mu, float* __restrict__ rs)
{
    long t = (long)blockIdx.x * 256 + threadIdx.x;   // over B*N
    int b = (int)(t >> 16);
    int n = (int)(t & 65535);
    const float* xb = X + (long)b * 128 * N_HW + n;
    float s = 0.f, s2 = 0.f;
    #pragma unroll 8
    for (int c = 0; c < 128; ++c) {
        float v = xb[(long)c * N_HW];
        s += v; s2 += v * v;
    }
    float m = s * (1.f/128.f);
    float var = fmaxf(s2 * (1.f/128.f) - m*m, 0.f);
    mu[t] = m;
    rs[t] = 1.0f / sqrtf(var + 1e-5f);
}

// ---------------------------------------------------------------------------
// Tiled fp32 GEMM (single batch): Y[o][n] = sum_i W[o][i] * X[i][n]  (K=128)
// Tile: 128 outputs x 64 positions, 256 threads, 8x4 micro-tile.
// EPI==1: LN-affine epilogue  Y = rs[n]*(acc - mu[n]*S[o]) + bias[o]
// ---------------------------------------------------------------------------
template<int EPI>
__global__ __launch_bounds__(256) void gemm_kernel(
    const float* __restrict__ W, const float* __restrict__ X, float* __restrict__ Y,
    const float* __restrict__ muA, const float* __restrict__ rsA,
    const float* __restrict__ Svec, const float* __restrict__ bias)
{
    __shared__ float As[16][132];   // [k][o]
    __shared__ float Bs[16][68];    // [k][n]
    const int oBlk = blockIdx.y * 128;
    const int nBlk = blockIdx.x * 64;
    const int tid = threadIdx.x;
    const int tn = tid & 15;   // 16 groups of 4 positions
    const int to = tid >> 4;   // 16 groups of 8 outputs
    float acc[8][4];
    #pragma unroll
    for (int j = 0; j < 8; ++j)
        #pragma unroll
        for (int u = 0; u < 4; ++u) acc[j][u] = 0.f;

    for (int k0 = 0; k0 < 128; k0 += 16) {
        #pragma unroll
        for (int p = 0; p < 8; ++p) {
            int o = (tid >> 4) + p * 16;
            int kk = tid & 15;
            As[kk][o] = W[(long)(oBlk + o) * 128 + k0 + kk];
        }
        #pragma unroll
        for (int p = 0; p < 4; ++p) {
            int kk = (tid >> 6) + p * 4;
            int nn = tid & 63;
            Bs[kk][nn] = X[(long)(k0 + kk) * N_HW + nBlk + nn];
        }
        __syncthreads();
        #pragma unroll
        for (int kk = 0; kk < 16; ++kk) {
            float a[8], bx[4];
            #pragma unroll
            for (int j = 0; j < 8; ++j) a[j] = As[kk][to*8 + j];
            #pragma unroll
            for (int u = 0; u < 4; ++u) bx[u] = Bs[kk][tn*4 + u];
            #pragma unroll
            for (int j = 0; j < 8; ++j)
                #pragma unroll
                for (int u = 0; u < 4; ++u)
                    acc[j][u] += a[j] * bx[u];
        }
        __syncthreads();
    }

    const int n0 = nBlk + tn * 4;
    if (EPI == 1) {
        float muv[4], rsv[4];
        #pragma unroll
        for (int u = 0; u < 4; ++u) { muv[u] = muA[n0+u]; rsv[u] = rsA[n0+u]; }
        #pragma unroll
        for (int j = 0; j < 8; ++j) {
            int o = oBlk + to*8 + j;
            float Sv = Svec[o], bv = bias[o];
            float4 r;
            r.x = rsv[0]*(acc[j][0] - muv[0]*Sv) + bv;
            r.y = rsv[1]*(acc[j][1] - muv[1]*Sv) + bv;
            r.z = rsv[2]*(acc[j][2] - muv[2]*Sv) + bv;
            r.w = rsv[3]*(acc[j][3] - muv[3]*Sv) + bv;
            *reinterpret_cast<float4*>(Y + (long)o * N_HW + n0) = r;
        }
    } else {
        #pragma unroll
        for (int j = 0; j < 8; ++j) {
            int o = oBlk + to*8 + j;
            float4 r;
            r.x = acc[j][0]; r.y = acc[j][1]; r.z = acc[j][2]; r.w = acc[j][3];
            *reinterpret_cast<float4*>(Y + (long)o * N_HW + n0) = r;
        }
    }
}

// ---------------------------------------------------------------------------
// Depthwise 3x3 conv, zero padding, single batch. Block = one image row.
// ---------------------------------------------------------------------------
__global__ __launch_bounds__(256) void dwconv_kernel(
    const float* __restrict__ in, const float* __restrict__ wdw,
    float* __restrict__ out)
{
    const int w = threadIdx.x;
    const int h = blockIdx.x;
    const int c = blockIdx.y;
    const float* ib = in + (long)c * N_HW;
    const float* wk = wdw + c * 9;
    float acc = 0.f;
    #pragma unroll
    for (int dy = -1; dy <= 1; ++dy) {
        int y = h + dy;
        if ((unsigned)y >= 256u) continue;
        const float* row = ib + (long)y * 256;
        #pragma unroll
        for (int dx = -1; dx <= 1; ++dx) {
            int x = w + dx;
            if ((unsigned)x >= 256u) continue;
            acc += wk[(dy+1)*3 + (dx+1)] * row[x];
        }
    }
    out[(long)c * N_HW + (long)h * 256 + w] = acc;
}

// ---------------------------------------------------------------------------
// Per-head 16x16 Gram partials G = qp . kk^T over a chunk of positions, plus
// squared norms. No atomics: each (chunk,hd) block writes its own partials.
// Grid: (32 chunks, 8 heads). Block: 16 (ci,di) groups x 16 lanes.
// ---------------------------------------------------------------------------
__global__ __launch_bounds__(256) void gram_kernel(
    const float* __restrict__ qp, const float* __restrict__ kv,
    float* __restrict__ Gpart, float* __restrict__ nq2part, float* __restrict__ nk2part)
{
    const int chunk = blockIdx.x;   // 32 chunks of 2048 positions
    const int hd = blockIdx.y;
    const int tid = threadIdx.x;
    const int g = tid >> 4, ts = tid & 15;
    const int ci = g >> 2, di = g & 3;
    const float* qb = qp + (long)(hd*16 + ci*4) * N_HW;
    const float* kb = kv + (long)(hd*16 + di*4) * N_HW;
    const int base = chunk * 2048 + ts;
    float acc[4][4] = {};
    float aq[4] = {}, ak[4] = {};
    for (int it = 0; it < 128; ++it) {
        int n = base + it * 16;
        float qv[4], kvv[4];
        #pragma unroll
        for (int i = 0; i < 4; ++i) qv[i] = qb[(long)i * N_HW + n];
        #pragma unroll
        for (int j = 0; j < 4; ++j) kvv[j] = kb[(long)j * N_HW + n];
        #pragma unroll
        for (int i = 0; i < 4; ++i)
            #pragma unroll
            for (int j = 0; j < 4; ++j)
                acc[i][j] += qv[i] * kvv[j];
        if (di == 0) {
            #pragma unroll
            for (int i = 0; i < 4; ++i) aq[i] += qv[i]*qv[i];
        }
        if (ci == 0) {
            #pragma unroll
            for (int j = 0; j < 4; ++j) ak[j] += kvv[j]*kvv[j];
        }
    }
    #pragma unroll
    for (int off = 8; off >= 1; off >>= 1) {
        #pragma unroll
        for (int i = 0; i < 4; ++i) {
            #pragma unroll
            for (int j = 0; j < 4; ++j) acc[i][j] += __shfl_xor(acc[i][j], off, 16);
            aq[i] += __shfl_xor(aq[i], off, 16);
            ak[i] += __shfl_xor(ak[i], off, 16);
        }
    }
    if (ts == 0) {
        const int slot = chunk * 8 + hd;
        float* Gb = Gpart + (long)slot * 256;
        #pragma unroll
        for (int i = 0; i < 4; ++i)
            #pragma unroll
            for (int j = 0; j < 4; ++j)
                Gb[(ci*4+i)*16 + di*4+j] = acc[i][j];
        if (di == 0) {
            #pragma unroll
            for (int i = 0; i < 4; ++i) nq2part[slot*16 + ci*4 + i] = aq[i];
        }
        if (ci == 0) {
            #pragma unroll
            for (int j = 0; j < 4; ++j) nk2part[slot*16 + di*4 + j] = ak[j];
        }
    }
}

// ---------------------------------------------------------------------------
// Reduce partials; attn = softmax_d( G/(||q|| ||k||) * temp[h] );
// W2 = Wout . blockdiag(attn).  One block per head (8 blocks), single batch.
// ---------------------------------------------------------------------------
__global__ __launch_bounds__(256) void attn_w2_kernel(
    const float* __restrict__ Gpart, const float* __restrict__ nq2part,
    const float* __restrict__ nk2part, const float* __restrict__ temp,
    const float* __restrict__ Wout, float* __restrict__ W2)
{
    const int hd = blockIdx.x;
    const int tid = threadIdx.x;
    __shared__ float attnS[16][17];
    __shared__ float rnq[16], rnk[16];
    const int c = tid >> 4, d = tid & 15;

    float gsum = 0.f;
    for (int ch = 0; ch < 32; ++ch)
        gsum += Gpart[(long)(ch*8 + hd) * 256 + c*16 + d];
    if (tid < 16) {
        float s = 0.f;
        for (int ch = 0; ch < 32; ++ch) s += nq2part[(ch*8 + hd)*16 + tid];
        rnq[tid] = fmaxf(sqrtf(s), 1e-12f);
    } else if (tid < 32) {
        int dd = tid - 16;
        float s = 0.f;
        for (int ch = 0; ch < 32; ++ch) s += nk2part[(ch*8 + hd)*16 + dd];
        rnk[dd] = fmaxf(sqrtf(s), 1e-12f);
    }
    __syncthreads();

    {
        float sc = gsum / (rnq[c] * rnk[d]) * temp[hd];
        float m = sc;
        #pragma unroll
        for (int off = 8; off >= 1; off >>= 1) m = fmaxf(m, __shfl_xor(m, off, 16));
        float e = expf(sc - m);
        float sum = e;
        #pragma unroll
        for (int off = 8; off >= 1; off >>= 1) sum += __shfl_xor(sum, off, 16);
        attnS[c][d] = e / sum;
    }
    __syncthreads();
    {
        const int d2 = tid & 15, og = tid >> 4;
        #pragma unroll
        for (int r = 0; r < 8; ++r) {
            int o = og + r * 16;
            float acc = 0.f;
            #pragma unroll
            for (int cc = 0; cc < 16; ++cc)
                acc += Wout[o*128 + hd*16 + cc] * attnS[cc][d2];
            W2[(long)o*128 + hd*16 + d2] = acc;
        }
    }
}

// ---------------------------------------------------------------------------
extern "C" void kernel_launch(void* const* d_in, const int* in_sizes, int n_in,
                              void* d_out, int out_size, void* d_ws, size_t ws_size,
                              hipStream_t stream)
{
    const float* q       = (const float*)d_in[0];
    const float* k       = (const float*)d_in[1];
    const float* ln_q_w  = (const float*)d_in[2];
    const float* ln_q_b  = (const float*)d_in[3];
    const float* ln_k_w  = (const float*)d_in[4];
    const float* ln_k_b  = (const float*)d_in[5];
    const float* Wq      = (const float*)d_in[6];
    const float* Wkv     = (const float*)d_in[7];
    const float* Wq_dw   = (const float*)d_in[8];
    const float* Wkv_dw  = (const float*)d_in[9];
    const float* Wout    = (const float*)d_in[10];
    const float* temp    = (const float*)d_in[11];
    float* out = (float*)d_out;

    // Workspace layout (bytes), peak ~139 MiB:
    //   bufA [0, 64 MiB): qp_pre uses first 32 MiB, then kv_pre uses all 64 MiB
    //   bufB [64 MiB, 128 MiB): kv post-dwconv (kk rows 0..127, vv rows 128..255)
    //   small [128 MiB, ...): LN stats, folded weights, gram partials, W2
    char* ws = (char*)d_ws;
    float* bufA   = (float*)(ws + 0L);                 // 64 MiB
    float* bufB   = (float*)(ws + 67108864L);          // 64 MiB
    float* mu_q   = (float*)(ws + 134217728L);         // B*N
    float* rs_q   = mu_q + 262144;
    float* mu_k   = rs_q + 262144;
    float* rs_k   = mu_k + 262144;
    float* Wqf    = rs_k + 262144;     // 128*128
    float* biasq  = Wqf + 16384;       // 128
    float* Sq     = biasq + 128;       // 128
    float* Wkvf   = Sq + 128;          // 256*128
    float* biaskv = Wkvf + 32768;      // 256
    float* Skv    = biaskv + 256;      // 256
    float* Gpart  = Skv + 256;         // 32*8*256 = 65536
    float* nq2p   = Gpart + 65536;     // 32*8*16 = 4096
    float* nk2p   = nq2p + 4096;       // 4096
    float* W2     = nk2p + 4096;       // 128*128

    fold_kernel<<<2, 192, 0, stream>>>(Wq, ln_q_w, ln_q_b, Wkv, ln_k_w, ln_k_b,
                                       Wqf, biasq, Sq, Wkvf, biaskv, Skv);

    lnstats_kernel<<<1024, 256, 0, stream>>>(q, mu_q, rs_q);
    lnstats_kernel<<<1024, 256, 0, stream>>>(k, mu_k, rs_k);

    for (int b = 0; b < BATCH; ++b) {
        const long big = (long)128 * N_HW;     // elements per (batch,128ch) slab
        const float* qb = q + (long)b * big;
        const float* kb = k + (long)b * big;
        float* outb = out + (long)b * big;
        float* qp = outb;                       // d_out slice as scratch (dead until final GEMM)

        // qp_pre = conv1x1(LN(q)) in bufA[0,32MiB)
        gemm_kernel<1><<<dim3(1024, 1, 1), 256, 0, stream>>>(
            Wqf, qb, bufA, mu_q + (long)b * N_HW, rs_q + (long)b * N_HW, Sq, biasq);
        // qp = dwconv(qp_pre) -> d_out slice
        dwconv_kernel<<<dim3(256, 128, 1), 256, 0, stream>>>(bufA, Wq_dw, qp);

        // kv_pre = conv1x1(LN(k)) in bufA[0,64MiB)  (overwrites consumed qp_pre)
        gemm_kernel<1><<<dim3(1024, 2, 1), 256, 0, stream>>>(
            Wkvf, kb, bufA, mu_k + (long)b * N_HW, rs_k + (long)b * N_HW, Skv, biaskv);
        // kv = dwconv(kv_pre) -> bufB
        dwconv_kernel<<<dim3(256, 256, 1), 256, 0, stream>>>(bufA, Wkv_dw, bufB);

        // Gram partials over qp (128ch) x kk (bufB rows 0..127)
        gram_kernel<<<dim3(32, 8, 1), 256, 0, stream>>>(qp, bufB, Gpart, nq2p, nk2p);

        // attn + W2 = Wout . blockdiag(attn)
        attn_w2_kernel<<<8, 256, 0, stream>>>(Gpart, nq2p, nk2p, temp, Wout, W2);

        // out_b = W2 . vv   (vv = bufB rows 128..255) — overwrites qp scratch
        gemm_kernel<0><<<dim3(1024, 1, 1), 256, 0, stream>>>(
            W2, bufB + (long)128 * N_HW, outb, nullptr, nullptr, nullptr, nullptr);
    }
}